// Round 2
// baseline (270.767 us; speedup 1.0000x reference)
//
#include <hip/hip_runtime.h>
#include <hip/hip_bf16.h>
#include <math.h>

#define BATCH 32
#define NTOK 577
#define NPATCH 576
#define CDIM 768
#define HEADS 12
#define DHEAD 64
#define W3 2304
#define FT 404

// ---- workspace layout (float offsets) ----
#define WS_QCLS  0          // 32*768            -> 24576
#define WS_WTIL  24576      // 32*12*768         -> 319488
#define WS_DBIAS 319488     // 32*12             -> 319872
#define WS_DOTS  319872     // 32*12*577         -> 541440
#define WS_IND   541440     // 32*404 (as int)   -> 554368
#define WS_CA    554368     // 32*576 (fp32)     -> 572800

// ---- output layout (FLOAT32 element offsets; d_out is float*) ----
#define O_X      0ULL           // 32*577*768 = 14180352
#define O_INDEX  14180352ULL    // 32*404*768 = 9928704 -> 24109056
#define O_IND    24109056ULL    // 32*404     = 12928   -> 24121984
#define O_CA     24121984ULL    // 32*576     = 18432   -> 24140416
#define O_FT     24140416ULL

// K1: q_cls[b, col] = x[b,0,:] @ W_qkv[:, col] + b_qkv[col],  col in [0,768)
__global__ __launch_bounds__(256) void k_qcls(const float* __restrict__ x,
                                              const float* __restrict__ W,
                                              const float* __restrict__ bias,
                                              float* __restrict__ qcls) {
    __shared__ float xs[CDIM];
    const int b = blockIdx.x, chunk = blockIdx.y, tid = threadIdx.x;
    for (int i = tid; i < CDIM; i += 256) xs[i] = x[(size_t)b * NTOK * CDIM + i];
    __syncthreads();
    const int col = chunk * 256 + tid;
    float a0 = 0.f, a1 = 0.f, a2 = 0.f, a3 = 0.f;
    for (int c = 0; c < CDIM; c += 4) {
        a0 += xs[c]     * W[(size_t)c * W3 + col];
        a1 += xs[c + 1] * W[(size_t)(c + 1) * W3 + col];
        a2 += xs[c + 2] * W[(size_t)(c + 2) * W3 + col];
        a3 += xs[c + 3] * W[(size_t)(c + 3) * W3 + col];
    }
    qcls[b * CDIM + col] = (a0 + a1) + (a2 + a3) + bias[col];
}

// K2: wtil[b,h,c] = sum_d qcls[b,h*64+d] * W_qkv[c, 768 + h*64 + d]
//     dbias[b,h]  = sum_d qcls[b,h*64+d] * b_qkv[768 + h*64 + d]
__global__ __launch_bounds__(256) void k_wtil(const float* __restrict__ W,
                                              const float* __restrict__ bias,
                                              const float* __restrict__ qcls,
                                              float* __restrict__ wtil,
                                              float* __restrict__ dbias) {
    __shared__ float qs[DHEAD];
    const int b = blockIdx.x, h = blockIdx.y, tid = threadIdx.x;
    if (tid < DHEAD) qs[tid] = qcls[b * CDIM + h * DHEAD + tid];
    __syncthreads();
    if (tid < 64) {
        float t = qs[tid] * bias[CDIM + h * DHEAD + tid];
        #pragma unroll
        for (int off = 32; off; off >>= 1) t += __shfl_down(t, off);
        if (tid == 0) dbias[b * HEADS + h] = t;
    }
    for (int c = tid; c < CDIM; c += 256) {
        const float* wr = W + (size_t)c * W3 + CDIM + h * DHEAD;
        float acc = 0.f;
        #pragma unroll
        for (int d = 0; d < DHEAD; d += 4) {
            float4 a = *reinterpret_cast<const float4*>(wr + d);
            acc += a.x * qs[d] + a.y * qs[d + 1] + a.z * qs[d + 2] + a.w * qs[d + 3];
        }
        wtil[((size_t)b * HEADS + h) * CDIM + c] = acc;
    }
}

// K3: dots[b,h,j] = 0.125*(x[b,j,:]·wtil[b,h,:] + dbias[b,h]); also copy x -> out0 (f32)
__global__ __launch_bounds__(256) void k_dots(const float* __restrict__ x,
                                              const float* __restrict__ wtil,
                                              const float* __restrict__ dbias,
                                              float* __restrict__ dots,
                                              float* __restrict__ out0) {
    __shared__ float wt[HEADS * CDIM];   // 36 KB
    __shared__ float db[HEADS];
    const int b = blockIdx.x, tid = threadIdx.x;
    for (int i = tid; i < HEADS * CDIM; i += 256) wt[i] = wtil[(size_t)b * HEADS * CDIM + i];
    if (tid < HEADS) db[tid] = dbias[b * HEADS + tid];
    __syncthreads();
    const int wave = tid >> 6, lane = tid & 63;
    for (int it = 0; it < 8; it++) {
        const int j = blockIdx.y * 32 + it * 4 + wave;
        if (j >= NTOK) break;
        const float4* xp = reinterpret_cast<const float4*>(x + ((size_t)b * NTOK + j) * CDIM);
        float4* op = reinterpret_cast<float4*>(out0 + ((size_t)b * NTOK + j) * CDIM);
        float acc[HEADS];
        #pragma unroll
        for (int h = 0; h < HEADS; h++) acc[h] = 0.f;
        #pragma unroll
        for (int i = 0; i < 3; i++) {
            float4 a = xp[i * 64 + lane];
            op[i * 64 + lane] = a;
            const int cbase = i * 256 + lane * 4;
            #pragma unroll
            for (int h = 0; h < HEADS; h++) {
                float4 w = *reinterpret_cast<const float4*>(&wt[h * CDIM + cbase]);
                acc[h] += a.x * w.x + a.y * w.y + a.z * w.z + a.w * w.w;
            }
        }
        #pragma unroll
        for (int off = 32; off; off >>= 1)
            #pragma unroll
            for (int h = 0; h < HEADS; h++) acc[h] += __shfl_down(acc[h], off);
        if (lane == 0) {
            #pragma unroll
            for (int h = 0; h < HEADS; h++)
                dots[((size_t)b * HEADS + h) * NTOK + j] = 0.125f * (acc[h] + db[h]);
        }
    }
}

// K4: per batch: softmax over j per head, mean over heads -> class_attention
__global__ __launch_bounds__(256) void k_softmax(const float* __restrict__ dots,
                                                 float* __restrict__ ca_f32,
                                                 float* __restrict__ out3) {
    __shared__ float dl[HEADS * NTOK];   // 27.7 KB
    __shared__ float red[256];
    __shared__ float mh[HEADS], sh[HEADS];
    const int b = blockIdx.x, tid = threadIdx.x;
    for (int i = tid; i < HEADS * NTOK; i += 256) dl[i] = dots[(size_t)b * HEADS * NTOK + i];
    __syncthreads();
    for (int h = 0; h < HEADS; h++) {
        float m = -3.4e38f;
        for (int j = tid; j < NTOK; j += 256) m = fmaxf(m, dl[h * NTOK + j]);
        red[tid] = m; __syncthreads();
        for (int s = 128; s; s >>= 1) { if (tid < s) red[tid] = fmaxf(red[tid], red[tid + s]); __syncthreads(); }
        const float mm = red[0]; __syncthreads();
        float sum = 0.f;
        for (int j = tid; j < NTOK; j += 256) sum += expf(dl[h * NTOK + j] - mm);
        red[tid] = sum; __syncthreads();
        for (int s = 128; s; s >>= 1) { if (tid < s) red[tid] += red[tid + s]; __syncthreads(); }
        if (tid == 0) { mh[h] = mm; sh[h] = red[0]; }
        __syncthreads();
    }
    for (int j = 1 + tid; j < NTOK; j += 256) {
        float ca = 0.f;
        #pragma unroll
        for (int h = 0; h < HEADS; h++) ca += expf(dl[h * NTOK + j] - mh[h]) / sh[h];
        ca *= (1.f / 12.f);
        ca_f32[b * NPATCH + (j - 1)] = ca;
        out3[(size_t)b * NPATCH + (j - 1)] = ca;
    }
}

// K5: per batch: rank-based top-404, compact ascending -> ind (ws int + out f32)
__global__ __launch_bounds__(576) void k_topk(const float* __restrict__ ca,
                                              int* __restrict__ ind_ws,
                                              float* __restrict__ out2,
                                              float* __restrict__ out4,
                                              int write_ft) {
    __shared__ unsigned int vals[NPATCH];
    __shared__ int flags[NPATCH];
    const int b = blockIdx.x, tid = threadIdx.x;
    // class_attention is strictly positive -> float bits order == value order
    const unsigned int myv = __float_as_uint(ca[b * NPATCH + tid]);
    vals[tid] = myv;
    __syncthreads();
    int rank = 0;
    for (int j = 0; j < NPATCH; j++) {
        const unsigned int v = vals[j];
        rank += (v > myv) || (v == myv && j < tid);  // tie: lower index wins (jax top_k)
    }
    flags[tid] = (rank < FT) ? 1 : 0;
    __syncthreads();
    if (flags[tid]) {
        int pos = 0;
        for (int j = 0; j < NPATCH; j++) pos += (j < tid) ? flags[j] : 0;
        ind_ws[b * FT + pos] = tid;
        out2[(size_t)b * FT + pos] = (float)tid;
    }
    if (b == 0 && tid == 0 && write_ft) out4[0] = (float)FT;
}

// K6: index[b,t,c] = ind[b,t] broadcast over c, as f32
__global__ __launch_bounds__(256) void k_bcast(const int* __restrict__ ind,
                                               float* __restrict__ out1) {
    const unsigned int g = blockIdx.x * 256u + threadIdx.x;
    const unsigned int e = g * 4u;               // element index, total = 9928704 = 9696*1024 exactly
    const unsigned int row = e / CDIM;           // b*FT + t
    const float v = (float)ind[row];
    float4 o; o.x = v; o.y = v; o.z = v; o.w = v;
    *reinterpret_cast<float4*>(out1 + e) = o;
}

extern "C" void kernel_launch(void* const* d_in, const int* in_sizes, int n_in,
                              void* d_out, int out_size, void* d_ws, size_t ws_size,
                              hipStream_t stream) {
    const float* x  = (const float*)d_in[0];
    const float* W  = (const float*)d_in[2];   // W_qkv [768, 2304]
    const float* bq = (const float*)d_in[3];   // b_qkv [2304]
    float* ws = (float*)d_ws;
    float* out = (float*)d_out;

    k_qcls<<<dim3(BATCH, 3), 256, 0, stream>>>(x, W, bq, ws + WS_QCLS);
    k_wtil<<<dim3(BATCH, HEADS), 256, 0, stream>>>(W, bq, ws + WS_QCLS, ws + WS_WTIL, ws + WS_DBIAS);
    k_dots<<<dim3(BATCH, 19), 256, 0, stream>>>(x, ws + WS_WTIL, ws + WS_DBIAS, ws + WS_DOTS, out + O_X);
    k_softmax<<<BATCH, 256, 0, stream>>>(ws + WS_DOTS, ws + WS_CA, out + O_CA);
    const int write_ft = (out_size > (int)O_FT) ? 1 : 0;
    k_topk<<<BATCH, 576, 0, stream>>>(ws + WS_CA, (int*)(ws + WS_IND), out + O_IND, out + O_FT, write_ft);
    k_bcast<<<9696, 256, 0, stream>>>((const int*)(ws + WS_IND), out + O_INDEX);
}

// Round 3
// 226.073 us; speedup vs baseline: 1.1977x; 1.1977x over previous
//
#include <hip/hip_runtime.h>
#include <hip/hip_bf16.h>
#include <math.h>

#define BATCH 32
#define NTOK 577
#define NPATCH 576
#define CDIM 768
#define HEADS 12
#define DHEAD 64
#define W3 2304
#define FT 404

// ---- workspace layout (float offsets) ----
#define WS_WTIL  24576      // 32*12*768         -> 319488
#define WS_DBIAS 319488     // 32*12             -> 319872
#define WS_DOTS  319872     // 32*12*577         -> 541440
#define WS_IND   541440     // 32*404 (as int)   -> 554368

// ---- output layout (FLOAT32 element offsets; d_out is float*) ----
#define O_X      0ULL           // 32*577*768 = 14180352
#define O_INDEX  14180352ULL    // 32*404*768 = 9928704 -> 24109056
#define O_IND    24109056ULL    // 32*404     = 12928   -> 24121984
#define O_CA     24121984ULL    // 32*576     = 18432   -> 24140416
#define O_FT     24140416ULL

// K_fold: per (b,h): q[d] = x[b,0,:]·W_qkv[:, h*64+d] + b_qkv[h*64+d]
//         wtil[b,h,c] = sum_d q[d] * W_qkv[c, 768 + h*64 + d]
//         dbias[b,h]  = sum_d q[d] * b_qkv[768 + h*64 + d]
__global__ __launch_bounds__(256) void k_fold(const float* __restrict__ x,
                                              const float* __restrict__ W,
                                              const float* __restrict__ bias,
                                              float* __restrict__ wtil,
                                              float* __restrict__ dbias) {
    __shared__ float x0s[CDIM];   // CLS token, 3 KB
    __shared__ float red[256];
    __shared__ float qs[DHEAD];
    const int b = blockIdx.x, h = blockIdx.y, tid = threadIdx.x;
    for (int i = tid; i < CDIM; i += 256) x0s[i] = x[(size_t)b * NTOK * CDIM + i];
    __syncthreads();
    // q-part: thread (seg,d) sums c in [seg*192,(seg+1)*192) of x0[c]*W[c, h*64+d]
    {
        const int d = tid & 63, seg = tid >> 6;
        const float* Wq = W + (size_t)(h * DHEAD + d);
        float acc = 0.f;
        const int c0 = seg * 192;
        #pragma unroll 8
        for (int c = c0; c < c0 + 192; c++)
            acc += x0s[c] * Wq[(size_t)c * W3];
        red[tid] = acc;
    }
    __syncthreads();
    if (tid < DHEAD) {
        float q = red[tid] + red[tid + 64] + red[tid + 128] + red[tid + 192]
                + bias[h * DHEAD + tid];
        qs[tid] = q;
        float t = q * bias[CDIM + h * DHEAD + tid];
        #pragma unroll
        for (int off = 32; off; off >>= 1) t += __shfl_down(t, off);
        if (tid == 0) dbias[b * HEADS + h] = t;
    }
    __syncthreads();
    for (int c = tid; c < CDIM; c += 256) {
        const float* wr = W + (size_t)c * W3 + CDIM + h * DHEAD;
        float acc = 0.f;
        #pragma unroll
        for (int d = 0; d < DHEAD; d += 4) {
            float4 a = *reinterpret_cast<const float4*>(wr + d);
            acc += a.x * qs[d] + a.y * qs[d + 1] + a.z * qs[d + 2] + a.w * qs[d + 3];
        }
        wtil[((size_t)b * HEADS + h) * CDIM + c] = acc;
    }
}

// K_dots: dots[b,h,j] = 0.125*(x[b,j,:]·wtil[b,h,:] + dbias[b,h]); fused x->out0 copy
__global__ __launch_bounds__(256) void k_dots(const float* __restrict__ x,
                                              const float* __restrict__ wtil,
                                              const float* __restrict__ dbias,
                                              float* __restrict__ dots,
                                              float* __restrict__ out0) {
    __shared__ float wt[HEADS * CDIM];   // 36 KB
    __shared__ float db[HEADS];
    const int b = blockIdx.x, tid = threadIdx.x;
    for (int i = tid; i < HEADS * CDIM; i += 256) wt[i] = wtil[(size_t)b * HEADS * CDIM + i];
    if (tid < HEADS) db[tid] = dbias[b * HEADS + tid];
    __syncthreads();
    const int wave = tid >> 6, lane = tid & 63;
    for (int it = 0; it < 8; it++) {
        const int j = blockIdx.y * 32 + it * 4 + wave;
        if (j >= NTOK) break;
        const float4* xp = reinterpret_cast<const float4*>(x + ((size_t)b * NTOK + j) * CDIM);
        float4* op = reinterpret_cast<float4*>(out0 + ((size_t)b * NTOK + j) * CDIM);
        float acc[HEADS];
        #pragma unroll
        for (int h = 0; h < HEADS; h++) acc[h] = 0.f;
        #pragma unroll
        for (int i = 0; i < 3; i++) {
            float4 a = xp[i * 64 + lane];
            op[i * 64 + lane] = a;
            const int cbase = i * 256 + lane * 4;
            #pragma unroll
            for (int h = 0; h < HEADS; h++) {
                float4 w = *reinterpret_cast<const float4*>(&wt[h * CDIM + cbase]);
                acc[h] += a.x * w.x + a.y * w.y + a.z * w.z + a.w * w.w;
            }
        }
        #pragma unroll
        for (int off = 32; off; off >>= 1)
            #pragma unroll
            for (int h = 0; h < HEADS; h++) acc[h] += __shfl_xor(acc[h], off);
        if (lane == 0) {
            #pragma unroll
            for (int h = 0; h < HEADS; h++)
                dots[((size_t)b * HEADS + h) * NTOK + j] = 0.125f * (acc[h] + db[h]);
        }
    }
}

// K_catopk: per batch (768 thr = 12 waves): wave h does softmax stats for head h
// (shfl-only), then ca = mean_h softmax, then rank-based top-404 + compaction.
__global__ __launch_bounds__(768) void k_catopk(const float* __restrict__ dots,
                                                float* __restrict__ ca_out,
                                                float* __restrict__ ind_out,
                                                float* __restrict__ ft_out,
                                                int* __restrict__ ind_ws,
                                                int write_ft) {
    __shared__ float dl[HEADS * NTOK];   // 27.7 KB
    __shared__ float mh[HEADS], sh[HEADS];
    __shared__ unsigned int vals[NPATCH];
    __shared__ int flags[NPATCH];
    const int b = blockIdx.x, tid = threadIdx.x;
    for (int i = tid; i < HEADS * NTOK; i += 768) dl[i] = dots[(size_t)b * HEADS * NTOK + i];
    __syncthreads();
    {
        const int w = tid >> 6, lane = tid & 63;   // w in [0,12): one wave per head
        const float* row = dl + w * NTOK;
        float m = -3.4e38f;
        for (int j = lane; j < NTOK; j += 64) m = fmaxf(m, row[j]);
        #pragma unroll
        for (int off = 32; off; off >>= 1) m = fmaxf(m, __shfl_xor(m, off));
        float s = 0.f;
        for (int j = lane; j < NTOK; j += 64) s += expf(row[j] - m);
        #pragma unroll
        for (int off = 32; off; off >>= 1) s += __shfl_xor(s, off);
        if (lane == 0) { mh[w] = m; sh[w] = s; }
    }
    __syncthreads();
    if (tid < NPATCH) {
        float ca = 0.f;
        #pragma unroll
        for (int h = 0; h < HEADS; h++)
            ca += expf(dl[h * NTOK + 1 + tid] - mh[h]) / sh[h];
        ca *= (1.f / 12.f);
        ca_out[(size_t)b * NPATCH + tid] = ca;
        vals[tid] = __float_as_uint(ca);   // ca > 0 -> bit order == value order
    }
    __syncthreads();
    if (tid < NPATCH) {
        const unsigned int myv = vals[tid];
        int rank = 0;
        for (int j = 0; j < NPATCH; j++) {
            const unsigned int v = vals[j];
            rank += (v > myv) || (v == myv && j < tid);  // tie: lower index first (jax)
        }
        flags[tid] = (rank < FT) ? 1 : 0;
    }
    __syncthreads();
    if (tid < NPATCH && flags[tid]) {
        int pos = 0;
        for (int j = 0; j < tid; j++) pos += flags[j];
        ind_ws[b * FT + pos] = tid;
        ind_out[(size_t)b * FT + pos] = (float)tid;
    }
    if (b == 0 && tid == 0 && write_ft) ft_out[0] = (float)FT;
}

// K_bcast: index[b,t,c] = ind[b,t] broadcast over c, as f32
__global__ __launch_bounds__(256) void k_bcast(const int* __restrict__ ind,
                                               float* __restrict__ out1) {
    const unsigned int g = blockIdx.x * 256u + threadIdx.x;
    const unsigned int e = g * 4u;               // total = 9928704 = 9696*1024 exactly
    const unsigned int row = e / CDIM;           // b*FT + t
    const float v = (float)ind[row];
    float4 o; o.x = v; o.y = v; o.z = v; o.w = v;
    *reinterpret_cast<float4*>(out1 + e) = o;
}

extern "C" void kernel_launch(void* const* d_in, const int* in_sizes, int n_in,
                              void* d_out, int out_size, void* d_ws, size_t ws_size,
                              hipStream_t stream) {
    const float* x  = (const float*)d_in[0];
    const float* W  = (const float*)d_in[2];   // W_qkv [768, 2304]
    const float* bq = (const float*)d_in[3];   // b_qkv [2304]
    float* ws = (float*)d_ws;
    float* out = (float*)d_out;

    k_fold<<<dim3(BATCH, HEADS), 256, 0, stream>>>(x, W, bq, ws + WS_WTIL, ws + WS_DBIAS);
    k_dots<<<dim3(BATCH, 19), 256, 0, stream>>>(x, ws + WS_WTIL, ws + WS_DBIAS, ws + WS_DOTS, out + O_X);
    const int write_ft = (out_size > (int)O_FT) ? 1 : 0;
    k_catopk<<<BATCH, 768, 0, stream>>>(ws + WS_DOTS, out + O_CA, out + O_IND, out + O_FT,
                                        (int*)(ws + WS_IND), write_ft);
    k_bcast<<<9696, 256, 0, stream>>>((const int*)(ws + WS_IND), out + O_INDEX);
}